// Round 2
// baseline (74.449 us; speedup 1.0000x reference)
//
#include <hip/hip_runtime.h>
#include <math.h>

#define N_CELLS_C 100000
#define N_ISO_C 16
#define KP1_C 31
#define LANES_PER_CELL 8
#define T_PER_LANE 4            // ceil(30 / 8)
#define BLOCK 256
#define CELLS_PER_BLOCK (BLOCK / LANES_PER_CELL)   // 32

// Detect whether the index buffer is int64 (odd int32 words all zero) or int32.
__global__ void detect_idx_kernel(const int* __restrict__ idx32, int* __restrict__ flag) {
    if (threadIdx.x == 0) {
        int is64 = 1;
        for (int t = 0; t < 64; ++t) {
            if (idx32[2 * t + 1] != 0) { is64 = 0; break; }
        }
        *flag = is64;  // 1 => elements are 8 bytes, 0 => 4 bytes
    }
}

__global__ __launch_bounds__(BLOCK) void cost_kernel(
    const float* __restrict__ unsplice,
    const float* __restrict__ splices,
    const float* __restrict__ unsplice_predict,
    const float* __restrict__ splice_predicts,
    const char*  __restrict__ idx_bytes,
    const int*   __restrict__ flag,
    float*       __restrict__ partials)
{
    const int tid  = threadIdx.x;
    const int sub  = tid & (LANES_PER_CELL - 1);
    const int cell = blockIdx.x * CELLS_PER_BLOCK + (tid >> 3);
    const int shift = (*flag) ? 3 : 2;              // log2(bytes per index)

    float cost = 0.0f;
    if (cell < N_CELLS_C) {
        const float u_i  = unsplice[cell];
        const float up_i = unsplice_predict[cell];

        float s_i[N_ISO_C];
        float v[N_ISO_C];
        const float4* srow  = (const float4*)(splices         + (long long)cell * N_ISO_C);
        const float4* sprow = (const float4*)(splice_predicts + (long long)cell * N_ISO_C);

        const float uv = up_i - u_i;
        float vn2 = uv * uv;
        #pragma unroll
        for (int q = 0; q < 4; ++q) {
            float4 s4  = srow[q];
            float4 sp4 = sprow[q];
            float d0 = sp4.x - s4.x, d1 = sp4.y - s4.y, d2 = sp4.z - s4.z, d3 = sp4.w - s4.w;
            s_i[4*q+0] = s4.x; s_i[4*q+1] = s4.y; s_i[4*q+2] = s4.z; s_i[4*q+3] = s4.w;
            v[4*q+0] = d0; v[4*q+1] = d1; v[4*q+2] = d2; v[4*q+3] = d3;
            vn2 += d0*d0 + d1*d1 + d2*d2 + d3*d3;
        }
        // max_k (dot_k * rsqrt(nn2_k)) * (1/|v|)  — positive scale commutes with max;
        // zero norms force cos contribution to 0 (matches ref: denom==0 -> 1, dot==0).
        const float inv_vi = (vn2 > 0.0f) ? rsqrtf(vn2) : 0.0f;

        const long long base = (long long)cell * KP1_C;

        // Preload indices (independent loads)
        int jv[T_PER_LANE];
        #pragma unroll
        for (int t = 0; t < T_PER_LANE; ++t) {
            int k = 1 + sub + LANES_PER_CELL * t;
            if (k > 30) k = 30;                      // duplicate last neighbor (safe under max)
            jv[t] = *(const int*)(idx_bytes + ((base + k) << shift));
        }
        // Preload scalar gathers (independent loads)
        float unv[T_PER_LANE];
        #pragma unroll
        for (int t = 0; t < T_PER_LANE; ++t) unv[t] = unsplice[jv[t]];

        float maxq = -INFINITY;                      // max of dot * rsqrt(nn2)
        #pragma unroll
        for (int t = 0; t < T_PER_LANE; ++t) {
            const int j = jv[t];
            const float un = unv[t] - u_i;
            float dot = uv * un;
            float nn2 = un * un;
            const float4* nrow = (const float4*)(splices + (long long)j * N_ISO_C);
            #pragma unroll
            for (int q = 0; q < 4; ++q) {
                float4 n4 = nrow[q];
                float d0 = n4.x - s_i[4*q+0];
                float d1 = n4.y - s_i[4*q+1];
                float d2 = n4.z - s_i[4*q+2];
                float d3 = n4.w - s_i[4*q+3];
                dot += v[4*q+0]*d0 + v[4*q+1]*d1 + v[4*q+2]*d2 + v[4*q+3]*d3;
                nn2 += d0*d0 + d1*d1 + d2*d2 + d3*d3;
            }
            const float rn = (nn2 > 0.0f) ? rsqrtf(nn2) : 0.0f;
            maxq = fmaxf(maxq, dot * rn);
        }
        // max across the 8 lanes of this cell's group
        maxq = fmaxf(maxq, __shfl_xor(maxq, 1));
        maxq = fmaxf(maxq, __shfl_xor(maxq, 2));
        maxq = fmaxf(maxq, __shfl_xor(maxq, 4));
        if (sub == 0) cost = 1.0f - maxq * inv_vi;
    }

    // block tree-sum (deterministic)
    for (int off = 32; off > 0; off >>= 1) cost += __shfl_down(cost, off);
    __shared__ float wsum[BLOCK / 64];
    const int wave = tid >> 6;
    const int lane = tid & 63;
    if (lane == 0) wsum[wave] = cost;
    __syncthreads();
    if (tid == 0) {
        float s = 0.0f;
        #pragma unroll
        for (int w = 0; w < BLOCK / 64; ++w) s += wsum[w];
        partials[blockIdx.x] = s;
    }
}

__global__ __launch_bounds__(BLOCK) void final_reduce_kernel(
    const float* __restrict__ partials, int nparts, float* __restrict__ out)
{
    float s = 0.0f;
    for (int i = threadIdx.x; i < nparts; i += BLOCK) s += partials[i];
    for (int off = 32; off > 0; off >>= 1) s += __shfl_down(s, off);
    __shared__ float wsum[BLOCK / 64];
    if ((threadIdx.x & 63) == 0) wsum[threadIdx.x >> 6] = s;
    __syncthreads();
    if (threadIdx.x == 0) {
        float t = 0.0f;
        #pragma unroll
        for (int w = 0; w < BLOCK / 64; ++w) t += wsum[w];
        out[0] = t / (float)N_CELLS_C;
    }
}

extern "C" void kernel_launch(void* const* d_in, const int* in_sizes, int n_in,
                              void* d_out, int out_size, void* d_ws, size_t ws_size,
                              hipStream_t stream) {
    const float* unsplice         = (const float*)d_in[0];
    const float* splices          = (const float*)d_in[1];
    const float* unsplice_predict = (const float*)d_in[2];
    const float* splice_predicts  = (const float*)d_in[3];
    const char*  idx_bytes        = (const char*)d_in[4];
    float* out = (float*)d_out;

    int*   flag     = (int*)d_ws;
    float* partials = (float*)((char*)d_ws + 256);

    const int nblocks = (N_CELLS_C + CELLS_PER_BLOCK - 1) / CELLS_PER_BLOCK;

    detect_idx_kernel<<<1, 64, 0, stream>>>((const int*)idx_bytes, flag);
    cost_kernel<<<nblocks, BLOCK, 0, stream>>>(
        unsplice, splices, unsplice_predict, splice_predicts,
        idx_bytes, flag, partials);
    final_reduce_kernel<<<1, BLOCK, 0, stream>>>(partials, nblocks, out);
}

// Round 3
// 57.212 us; speedup vs baseline: 1.3013x; 1.3013x over previous
//
#include <hip/hip_runtime.h>
#include <math.h>

#define N_CELLS_C 100000
#define N_ISO_C 16
#define KP1_C 31
#define BLOCK 256
#define CELLS_PER_BLOCK (BLOCK / 4)   // 64 cells, 4 lanes each

// Detect whether the index buffer is int64 (odd int32 words all zero) or int32.
__global__ void detect_idx_kernel(const int* __restrict__ idx32, int* __restrict__ flag) {
    if (threadIdx.x == 0) {
        int is64 = 1;
        for (int t = 0; t < 64; ++t) {
            if (idx32[2 * t + 1] != 0) { is64 = 0; break; }
        }
        *flag = is64;  // 1 => elements are 8 bytes, 0 => 4 bytes
    }
}

__global__ __launch_bounds__(BLOCK) void cost_kernel(
    const float* __restrict__ unsplice,
    const float* __restrict__ splices,
    const float* __restrict__ unsplice_predict,
    const float* __restrict__ splice_predicts,
    const char*  __restrict__ idx_bytes,
    const int*   __restrict__ flag,
    float*       __restrict__ partials)
{
    const int tid  = threadIdx.x;
    const int q    = tid & 3;                       // quarter owned by this lane
    const int cell = blockIdx.x * CELLS_PER_BLOCK + (tid >> 2);
    const int shift = (*flag) ? 3 : 2;              // log2(bytes per index)

    float cost = 0.0f;
    if (cell < N_CELLS_C) {
        const float u_i  = unsplice[cell];
        const float uv   = unsplice_predict[cell] - u_i;

        // lane q loads quarter q of this cell's row — wave-contiguous.
        const float4 s4  = *(const float4*)(splices         + (long long)cell * N_ISO_C + 4 * q);
        const float4 sp4 = *(const float4*)(splice_predicts + (long long)cell * N_ISO_C + 4 * q);
        const float v0 = sp4.x - s4.x, v1 = sp4.y - s4.y, v2 = sp4.z - s4.z, v3 = sp4.w - s4.w;

        float vp = v0*v0 + v1*v1 + v2*v2 + v3*v3;   // partial |v|^2 (this quarter)
        vp += __shfl_xor(vp, 1);
        vp += __shfl_xor(vp, 2);
        const float vn2 = vp + uv * uv;
        // max_k (dot_k * rsqrt(nn2_k)) * (1/|v|) — positive scale commutes with max;
        // zero norms force contribution to 0 (ref: denom==0 -> 1 with dot==0).
        const float inv_vi = (vn2 > 0.0f) ? rsqrtf(vn2) : 0.0f;

        const long long base = (long long)cell * KP1_C;
        float maxq = -INFINITY;

        #pragma unroll
        for (int k = 1; k < KP1_C; ++k) {
            const int j = *(const int*)(idx_bytes + ((base + k) << shift)); // broadcast
            const float unj = unsplice[j];                                  // broadcast
            // one float4 per lane; 4 lanes cover the 64B row -> 1 line request
            const float4 n4 = *(const float4*)(splices + (long long)j * N_ISO_C + 4 * q);
            const float d0 = n4.x - s4.x;
            const float d1 = n4.y - s4.y;
            const float d2 = n4.z - s4.z;
            const float d3 = n4.w - s4.w;
            float dp = v0*d0 + v1*d1 + v2*d2 + v3*d3;
            float np = d0*d0 + d1*d1 + d2*d2 + d3*d3;
            dp += __shfl_xor(dp, 1);  np += __shfl_xor(np, 1);
            dp += __shfl_xor(dp, 2);  np += __shfl_xor(np, 2);
            const float un  = unj - u_i;
            const float dot = dp + uv * un;
            const float nn2 = np + un * un;
            const float rn  = (nn2 > 0.0f) ? rsqrtf(nn2) : 0.0f;
            maxq = fmaxf(maxq, dot * rn);
        }
        // butterfly left identical (dot,nn2) in all 4 lanes -> maxq already uniform
        if (q == 0) cost = 1.0f - maxq * inv_vi;
    }

    // block tree-sum (deterministic)
    for (int off = 32; off > 0; off >>= 1) cost += __shfl_down(cost, off);
    __shared__ float wsum[BLOCK / 64];
    const int wave = tid >> 6;
    const int lane = tid & 63;
    if (lane == 0) wsum[wave] = cost;
    __syncthreads();
    if (tid == 0) {
        float s = 0.0f;
        #pragma unroll
        for (int w = 0; w < BLOCK / 64; ++w) s += wsum[w];
        partials[blockIdx.x] = s;
    }
}

__global__ __launch_bounds__(BLOCK) void final_reduce_kernel(
    const float* __restrict__ partials, int nparts, float* __restrict__ out)
{
    float s = 0.0f;
    for (int i = threadIdx.x; i < nparts; i += BLOCK) s += partials[i];
    for (int off = 32; off > 0; off >>= 1) s += __shfl_down(s, off);
    __shared__ float wsum[BLOCK / 64];
    if ((threadIdx.x & 63) == 0) wsum[threadIdx.x >> 6] = s;
    __syncthreads();
    if (threadIdx.x == 0) {
        float t = 0.0f;
        #pragma unroll
        for (int w = 0; w < BLOCK / 64; ++w) t += wsum[w];
        out[0] = t / (float)N_CELLS_C;
    }
}

extern "C" void kernel_launch(void* const* d_in, const int* in_sizes, int n_in,
                              void* d_out, int out_size, void* d_ws, size_t ws_size,
                              hipStream_t stream) {
    const float* unsplice         = (const float*)d_in[0];
    const float* splices          = (const float*)d_in[1];
    const float* unsplice_predict = (const float*)d_in[2];
    const float* splice_predicts  = (const float*)d_in[3];
    const char*  idx_bytes        = (const char*)d_in[4];
    float* out = (float*)d_out;

    int*   flag     = (int*)d_ws;
    float* partials = (float*)((char*)d_ws + 256);

    const int nblocks = (N_CELLS_C + CELLS_PER_BLOCK - 1) / CELLS_PER_BLOCK;

    detect_idx_kernel<<<1, 64, 0, stream>>>((const int*)idx_bytes, flag);
    cost_kernel<<<nblocks, BLOCK, 0, stream>>>(
        unsplice, splices, unsplice_predict, splice_predicts,
        idx_bytes, flag, partials);
    final_reduce_kernel<<<1, BLOCK, 0, stream>>>(partials, nblocks, out);
}

// Round 4
// 50.623 us; speedup vs baseline: 1.4707x; 1.1302x over previous
//
#include <hip/hip_runtime.h>
#include <math.h>

#define N_CELLS_C 100000
#define N_ISO_C 16
#define KP1_C 31
#define BLOCK 256

typedef _Float16 hf2 __attribute__((ext_vector_type(2)));
union Rec16 { float4 f; hf2 h[4]; };

__device__ __forceinline__ float fdot2f(hf2 a, hf2 b, float c) {
    return __builtin_amdgcn_fdot2(a, b, c, false);
}

// Detect whether the index buffer is int64 (odd int32 words all zero) or int32.
__global__ void detect_idx_kernel(const int* __restrict__ idx32, int* __restrict__ flag) {
    if (threadIdx.x == 0) {
        int is64 = 1;
        for (int t = 0; t < 64; ++t) {
            if (idx32[2 * t + 1] != 0) { is64 = 0; break; }
        }
        *flag = is64;  // 1 => 8-byte indices, 0 => 4-byte
    }
}

// Pack per-cell fp16 record: half[32] = [s0..s15, u, 0...], 64B line-aligned.
// 2 lanes per cell; lane h packs s[8h..8h+7]; lane0 also writes (u,0..) tail,
// lane1 zeros the last 16B.
__global__ __launch_bounds__(BLOCK) void pack_kernel(
    const float* __restrict__ unsplice,
    const float* __restrict__ splices,
    char* __restrict__ rec)
{
    const int t = blockIdx.x * BLOCK + threadIdx.x;
    const int cell = t >> 1, h = t & 1;
    if (cell >= N_CELLS_C) return;
    const float4* srow = (const float4*)(splices + (long long)cell * N_ISO_C + 8 * h);
    const float4 a = srow[0];
    const float4 b = srow[1];
    Rec16 r;
    r.h[0] = hf2{(_Float16)a.x, (_Float16)a.y};
    r.h[1] = hf2{(_Float16)a.z, (_Float16)a.w};
    r.h[2] = hf2{(_Float16)b.x, (_Float16)b.y};
    r.h[3] = hf2{(_Float16)b.z, (_Float16)b.w};
    float4* dst = (float4*)(rec + ((long long)cell << 6));
    dst[h] = r.f;
    Rec16 tl;
    tl.f = float4{0.f, 0.f, 0.f, 0.f};
    if (h == 0) tl.h[0][0] = (_Float16)unsplice[cell];
    dst[2 + h] = tl.f;
}

// 8 lanes per cell: q=sub&3 owns 16B quarter of the 64B record (coalesced to
// one line per neighbor); h=sub>>2 splits even/odd neighbors.
__global__ __launch_bounds__(BLOCK) void cost_kernel_h(
    const float* __restrict__ unsplice,
    const float* __restrict__ splices,
    const float* __restrict__ unsplice_predict,
    const float* __restrict__ splice_predicts,
    const char*  __restrict__ idx_bytes,
    const int*   __restrict__ flag,
    const char*  __restrict__ rec,
    float*       __restrict__ partials)
{
    const int tid  = threadIdx.x;
    const int sub  = tid & 7;
    const int q    = sub & 3;
    const int h    = sub >> 2;
    const int cell = blockIdx.x * (BLOCK / 8) + (tid >> 3);   // grid is exact
    const int shift = (*flag) ? 3 : 2;

    // Own-cell record quarter (c) and predict quarter (p), built from fp32
    // sources with the SAME fp16 rounding as pack_kernel.
    Rec16 c, p;
    c.f = float4{0.f, 0.f, 0.f, 0.f};
    p.f = float4{0.f, 0.f, 0.f, 0.f};
    if (q < 2) {
        const float4* srow = (const float4*)(splices         + (long long)cell * N_ISO_C + 8 * q);
        const float4* prow = (const float4*)(splice_predicts + (long long)cell * N_ISO_C + 8 * q);
        const float4 a = srow[0], b = srow[1];
        const float4 pa = prow[0], pb = prow[1];
        c.h[0] = hf2{(_Float16)a.x, (_Float16)a.y};
        c.h[1] = hf2{(_Float16)a.z, (_Float16)a.w};
        c.h[2] = hf2{(_Float16)b.x, (_Float16)b.y};
        c.h[3] = hf2{(_Float16)b.z, (_Float16)b.w};
        p.h[0] = hf2{(_Float16)pa.x, (_Float16)pa.y};
        p.h[1] = hf2{(_Float16)pa.z, (_Float16)pa.w};
        p.h[2] = hf2{(_Float16)pb.x, (_Float16)pb.y};
        p.h[3] = hf2{(_Float16)pb.z, (_Float16)pb.w};
    } else if (q == 2) {
        c.h[0][0] = (_Float16)unsplice[cell];
        p.h[0][0] = (_Float16)unsplice_predict[cell];
    }
    const hf2 v0 = p.h[0] - c.h[0];
    const hf2 v1 = p.h[1] - c.h[1];
    const hf2 v2 = p.h[2] - c.h[2];
    const hf2 v3 = p.h[3] - c.h[3];

    float vp = fdot2f(v0, v0, fdot2f(v1, v1, fdot2f(v2, v2, fdot2f(v3, v3, 0.f))));
    vp += __shfl_xor(vp, 1);
    vp += __shfl_xor(vp, 2);
    const float inv_vi = (vp > 0.f) ? rsqrtf(vp) : 0.f;   // zero-norm -> cos 0 (ref: denom->1, dot 0)

    const long long base = (long long)cell * KP1_C;
    int jv[15];
    #pragma unroll
    for (int t = 0; t < 15; ++t) {
        const int k = 1 + h + 2 * t;                       // h=0: odd ks, h=1: even ks
        jv[t] = *(const int*)(idx_bytes + ((base + k) << shift));
    }

    float maxq = -INFINITY;
    #pragma unroll 5
    for (int t = 0; t < 15; ++t) {
        const Rec16 g = *(const Rec16*)(rec + ((long long)jv[t] << 6) + (q << 4));
        const hf2 d0 = g.h[0] - c.h[0];
        const hf2 d1 = g.h[1] - c.h[1];
        const hf2 d2 = g.h[2] - c.h[2];
        const hf2 d3 = g.h[3] - c.h[3];
        float dp = fdot2f(v0, d0, fdot2f(v1, d1, fdot2f(v2, d2, fdot2f(v3, d3, 0.f))));
        float np = fdot2f(d0, d0, fdot2f(d1, d1, fdot2f(d2, d2, fdot2f(d3, d3, 0.f))));
        dp += __shfl_xor(dp, 1);  np += __shfl_xor(np, 1);
        dp += __shfl_xor(dp, 2);  np += __shfl_xor(np, 2);
        const float rn = (np > 0.f) ? rsqrtf(np) : 0.f;
        maxq = fmaxf(maxq, dp * rn);
    }
    maxq = fmaxf(maxq, __shfl_xor(maxq, 4));               // merge even/odd halves

    float cost = (sub == 0) ? (1.0f - maxq * inv_vi) : 0.f;

    for (int off = 32; off > 0; off >>= 1) cost += __shfl_down(cost, off);
    __shared__ float wsum[BLOCK / 64];
    if ((tid & 63) == 0) wsum[tid >> 6] = cost;
    __syncthreads();
    if (tid == 0) {
        float s = 0.f;
        #pragma unroll
        for (int w = 0; w < BLOCK / 64; ++w) s += wsum[w];
        partials[blockIdx.x] = s;
    }
}

// -------- fp32 fallback (R3 kernel) used only if ws_size is too small -------
__global__ __launch_bounds__(BLOCK) void cost_kernel_f32(
    const float* __restrict__ unsplice,
    const float* __restrict__ splices,
    const float* __restrict__ unsplice_predict,
    const float* __restrict__ splice_predicts,
    const char*  __restrict__ idx_bytes,
    const int*   __restrict__ flag,
    float*       __restrict__ partials)
{
    const int tid  = threadIdx.x;
    const int q    = tid & 3;
    const int cell = blockIdx.x * (BLOCK / 4) + (tid >> 2);
    const int shift = (*flag) ? 3 : 2;

    float cost = 0.0f;
    if (cell < N_CELLS_C) {
        const float u_i = unsplice[cell];
        const float uv  = unsplice_predict[cell] - u_i;
        const float4 s4  = *(const float4*)(splices         + (long long)cell * N_ISO_C + 4 * q);
        const float4 sp4 = *(const float4*)(splice_predicts + (long long)cell * N_ISO_C + 4 * q);
        const float v0 = sp4.x - s4.x, v1 = sp4.y - s4.y, v2 = sp4.z - s4.z, v3 = sp4.w - s4.w;
        float vpp = v0*v0 + v1*v1 + v2*v2 + v3*v3;
        vpp += __shfl_xor(vpp, 1);
        vpp += __shfl_xor(vpp, 2);
        const float vn2 = vpp + uv * uv;
        const float inv_vi = (vn2 > 0.0f) ? rsqrtf(vn2) : 0.0f;
        const long long base = (long long)cell * KP1_C;
        float maxq = -INFINITY;
        #pragma unroll
        for (int k = 1; k < KP1_C; ++k) {
            const int j = *(const int*)(idx_bytes + ((base + k) << shift));
            const float unj = unsplice[j];
            const float4 n4 = *(const float4*)(splices + (long long)j * N_ISO_C + 4 * q);
            const float d0 = n4.x - s4.x, d1 = n4.y - s4.y, d2 = n4.z - s4.z, d3 = n4.w - s4.w;
            float dp = v0*d0 + v1*d1 + v2*d2 + v3*d3;
            float np = d0*d0 + d1*d1 + d2*d2 + d3*d3;
            dp += __shfl_xor(dp, 1);  np += __shfl_xor(np, 1);
            dp += __shfl_xor(dp, 2);  np += __shfl_xor(np, 2);
            const float un  = unj - u_i;
            const float dot = dp + uv * un;
            const float nn2 = np + un * un;
            const float rn  = (nn2 > 0.0f) ? rsqrtf(nn2) : 0.0f;
            maxq = fmaxf(maxq, dot * rn);
        }
        if (q == 0) cost = 1.0f - maxq * inv_vi;
    }
    for (int off = 32; off > 0; off >>= 1) cost += __shfl_down(cost, off);
    __shared__ float wsum[BLOCK / 64];
    if ((tid & 63) == 0) wsum[tid >> 6] = cost;
    __syncthreads();
    if (tid == 0) {
        float s = 0.0f;
        #pragma unroll
        for (int w = 0; w < BLOCK / 64; ++w) s += wsum[w];
        partials[blockIdx.x] = s;
    }
}

__global__ __launch_bounds__(BLOCK) void final_reduce_kernel(
    const float* __restrict__ partials, int nparts, float* __restrict__ out)
{
    float s = 0.0f;
    for (int i = threadIdx.x; i < nparts; i += BLOCK) s += partials[i];
    for (int off = 32; off > 0; off >>= 1) s += __shfl_down(s, off);
    __shared__ float wsum[BLOCK / 64];
    if ((threadIdx.x & 63) == 0) wsum[threadIdx.x >> 6] = s;
    __syncthreads();
    if (threadIdx.x == 0) {
        float t = 0.0f;
        #pragma unroll
        for (int w = 0; w < BLOCK / 64; ++w) t += wsum[w];
        out[0] = t / (float)N_CELLS_C;
    }
}

extern "C" void kernel_launch(void* const* d_in, const int* in_sizes, int n_in,
                              void* d_out, int out_size, void* d_ws, size_t ws_size,
                              hipStream_t stream) {
    const float* unsplice         = (const float*)d_in[0];
    const float* splices          = (const float*)d_in[1];
    const float* unsplice_predict = (const float*)d_in[2];
    const float* splice_predicts  = (const float*)d_in[3];
    const char*  idx_bytes        = (const char*)d_in[4];
    float* out = (float*)d_out;

    int*   flag     = (int*)d_ws;
    float* partials = (float*)((char*)d_ws + 256);
    char*  rec      = (char*)d_ws + (64 << 10);

    const size_t req = (size_t)(64 << 10) + (size_t)N_CELLS_C * 64;

    detect_idx_kernel<<<1, 64, 0, stream>>>((const int*)idx_bytes, flag);

    if (ws_size >= req) {
        const int pack_blocks = (2 * N_CELLS_C + BLOCK - 1) / BLOCK;
        pack_kernel<<<pack_blocks, BLOCK, 0, stream>>>(unsplice, splices, rec);
        const int nblocks = N_CELLS_C / (BLOCK / 8);   // 3125, exact
        cost_kernel_h<<<nblocks, BLOCK, 0, stream>>>(
            unsplice, splices, unsplice_predict, splice_predicts,
            idx_bytes, flag, rec, partials);
        final_reduce_kernel<<<1, BLOCK, 0, stream>>>(partials, nblocks, out);
    } else {
        const int nblocks = (N_CELLS_C + (BLOCK / 4) - 1) / (BLOCK / 4);
        cost_kernel_f32<<<nblocks, BLOCK, 0, stream>>>(
            unsplice, splices, unsplice_predict, splice_predicts,
            idx_bytes, flag, partials);
        final_reduce_kernel<<<1, BLOCK, 0, stream>>>(partials, nblocks, out);
    }
}

// Round 5
// 47.366 us; speedup vs baseline: 1.5718x; 1.0687x over previous
//
#include <hip/hip_runtime.h>
#include <math.h>

#define N_CELLS_C 100000
#define N_ISO_C 16
#define KP1_C 31
#define BLOCK 256

typedef _Float16 hf2 __attribute__((ext_vector_type(2)));
union Rec16 { float4 f; hf2 h[4]; };

__device__ __forceinline__ float fdot2f(hf2 a, hf2 b, float c) {
    return __builtin_amdgcn_fdot2(a, b, c, false);
}

// Per-wave index-dtype detect: int64 indices (< 2^17) have all odd int32
// words == 0; int32 random indices make that astronomically unlikely.
__device__ __forceinline__ int idx_shift(const char* idx_bytes) {
    const int lane = threadIdx.x & 63;
    int probe = 0;
    if (lane < 16) probe = ((const int*)idx_bytes)[2 * lane + 1];
    return __any(probe != 0) ? 2 : 3;   // bytes-per-index log2
}

// Pack: rec[cell] = 16 x fp16 splices (32B), u16[cell] = fp16 unsplice.
// 2 threads per cell; thread h packs dims 8h..8h+7 (16B coalesced store).
__global__ __launch_bounds__(BLOCK) void pack_kernel(
    const float* __restrict__ unsplice,
    const float* __restrict__ splices,
    char* __restrict__ rec,
    _Float16* __restrict__ u16)
{
    const int t = blockIdx.x * BLOCK + threadIdx.x;
    const int cell = t >> 1, h = t & 1;
    if (cell >= N_CELLS_C) return;
    const float* srow = splices + (long long)cell * N_ISO_C + 8 * h;
    const float4 a = *(const float4*)srow;
    const float4 b = *(const float4*)(srow + 4);
    Rec16 r;
    r.h[0] = hf2{(_Float16)a.x, (_Float16)a.y};
    r.h[1] = hf2{(_Float16)a.z, (_Float16)a.w};
    r.h[2] = hf2{(_Float16)b.x, (_Float16)b.y};
    r.h[3] = hf2{(_Float16)b.z, (_Float16)b.w};
    *(float4*)(rec + ((long long)cell << 5) + (h << 4)) = r.f;
    if (h == 0) u16[cell] = (_Float16)unsplice[cell];
}

// 8 lanes/cell: pair (h = sub>>1) handles neighbors k = 1+h+4t; lane w = sub&1
// owns the 16B half of the 32B record. One dwordx4 + one 2B u load per
// neighbor; pair-reduce with a single shfl_xor(1).
__global__ __launch_bounds__(BLOCK) void cost_kernel_h(
    const float* __restrict__ unsplice,
    const float* __restrict__ splices,
    const float* __restrict__ unsplice_predict,
    const float* __restrict__ splice_predicts,
    const char*  __restrict__ idx_bytes,
    const char*  __restrict__ rec,
    const _Float16* __restrict__ u16,
    float*       __restrict__ partials)
{
    const int tid  = threadIdx.x;
    const int sub  = tid & 7;
    const int w    = sub & 1;
    const int h    = sub >> 1;
    const int cell = blockIdx.x * (BLOCK / 8) + (tid >> 3);   // grid exact
    const int shift = idx_shift(idx_bytes);

    // Own-cell half in fp16 (same rounding as pack_kernel).
    const float* srow = splices         + (long long)cell * N_ISO_C + 8 * w;
    const float* prow = splice_predicts + (long long)cell * N_ISO_C + 8 * w;
    const float4 a  = *(const float4*)srow,  b  = *(const float4*)(srow + 4);
    const float4 pa = *(const float4*)prow,  pb = *(const float4*)(prow + 4);
    const hf2 c0{(_Float16)a.x,  (_Float16)a.y},  c1{(_Float16)a.z,  (_Float16)a.w};
    const hf2 c2{(_Float16)b.x,  (_Float16)b.y},  c3{(_Float16)b.z,  (_Float16)b.w};
    const hf2 q0{(_Float16)pa.x, (_Float16)pa.y}, q1{(_Float16)pa.z, (_Float16)pa.w};
    const hf2 q2{(_Float16)pb.x, (_Float16)pb.y}, q3{(_Float16)pb.z, (_Float16)pb.w};
    const hf2 v0 = q0 - c0, v1 = q1 - c1, v2 = q2 - c2, v3 = q3 - c3;

    const float u_i = (float)(_Float16)unsplice[cell];
    const float uv  = unsplice_predict[cell] - unsplice[cell];

    float vp = fdot2f(v0, v0, fdot2f(v1, v1, fdot2f(v2, v2, fdot2f(v3, v3, 0.f))));
    vp += __shfl_xor(vp, 1);
    const float vn2 = vp + uv * uv;
    const float inv_vi = (vn2 > 0.f) ? rsqrtf(vn2) : 0.f;   // zero-norm -> cost 1 (ref: denom->1, dot 0)

    const long long base = (long long)cell * KP1_C;
    int jv[8];
    #pragma unroll
    for (int t = 0; t < 8; ++t) {
        int k = 1 + h + 4 * t;
        if (k > 30) k = 30;                                  // duplicate (safe under max)
        jv[t] = *(const int*)(idx_bytes + ((base + k) << shift));
    }

    float maxq = -INFINITY;
    #pragma unroll
    for (int t = 0; t < 8; ++t) {
        const int j = jv[t];
        const float u_j = (float)u16[j];
        const Rec16 g = *(const Rec16*)(rec + ((long long)j << 5) + (w << 4));
        const hf2 d0 = g.h[0] - c0;
        const hf2 d1 = g.h[1] - c1;
        const hf2 d2 = g.h[2] - c2;
        const hf2 d3 = g.h[3] - c3;
        float dp = fdot2f(v0, d0, fdot2f(v1, d1, fdot2f(v2, d2, fdot2f(v3, d3, 0.f))));
        float np = fdot2f(d0, d0, fdot2f(d1, d1, fdot2f(d2, d2, fdot2f(d3, d3, 0.f))));
        dp += __shfl_xor(dp, 1);
        np += __shfl_xor(np, 1);
        const float un  = u_j - u_i;
        const float dot = dp + uv * un;
        const float nn2 = np + un * un;
        const float rn  = (nn2 > 0.f) ? rsqrtf(nn2) : 0.f;
        maxq = fmaxf(maxq, dot * rn);
    }
    maxq = fmaxf(maxq, __shfl_xor(maxq, 2));
    maxq = fmaxf(maxq, __shfl_xor(maxq, 4));

    float cost = (sub == 0) ? (1.0f - maxq * inv_vi) : 0.f;

    for (int off = 32; off > 0; off >>= 1) cost += __shfl_down(cost, off);
    __shared__ float wsum[BLOCK / 64];
    if ((tid & 63) == 0) wsum[tid >> 6] = cost;
    __syncthreads();
    if (tid == 0) {
        float s = 0.f;
        #pragma unroll
        for (int wv = 0; wv < BLOCK / 64; ++wv) s += wsum[wv];
        partials[blockIdx.x] = s;
    }
}

// -------- fp32 fallback (R3 kernel) used only if ws_size is too small -------
__global__ __launch_bounds__(BLOCK) void cost_kernel_f32(
    const float* __restrict__ unsplice,
    const float* __restrict__ splices,
    const float* __restrict__ unsplice_predict,
    const float* __restrict__ splice_predicts,
    const char*  __restrict__ idx_bytes,
    float*       __restrict__ partials)
{
    const int tid  = threadIdx.x;
    const int q    = tid & 3;
    const int cell = blockIdx.x * (BLOCK / 4) + (tid >> 2);
    const int shift = idx_shift(idx_bytes);

    float cost = 0.0f;
    if (cell < N_CELLS_C) {
        const float u_i = unsplice[cell];
        const float uv  = unsplice_predict[cell] - u_i;
        const float4 s4  = *(const float4*)(splices         + (long long)cell * N_ISO_C + 4 * q);
        const float4 sp4 = *(const float4*)(splice_predicts + (long long)cell * N_ISO_C + 4 * q);
        const float v0 = sp4.x - s4.x, v1 = sp4.y - s4.y, v2 = sp4.z - s4.z, v3 = sp4.w - s4.w;
        float vpp = v0*v0 + v1*v1 + v2*v2 + v3*v3;
        vpp += __shfl_xor(vpp, 1);
        vpp += __shfl_xor(vpp, 2);
        const float vn2 = vpp + uv * uv;
        const float inv_vi = (vn2 > 0.0f) ? rsqrtf(vn2) : 0.0f;
        const long long base = (long long)cell * KP1_C;
        float maxq = -INFINITY;
        #pragma unroll
        for (int k = 1; k < KP1_C; ++k) {
            const int j = *(const int*)(idx_bytes + ((base + k) << shift));
            const float unj = unsplice[j];
            const float4 n4 = *(const float4*)(splices + (long long)j * N_ISO_C + 4 * q);
            const float d0 = n4.x - s4.x, d1 = n4.y - s4.y, d2 = n4.z - s4.z, d3 = n4.w - s4.w;
            float dp = v0*d0 + v1*d1 + v2*d2 + v3*d3;
            float np = d0*d0 + d1*d1 + d2*d2 + d3*d3;
            dp += __shfl_xor(dp, 1);  np += __shfl_xor(np, 1);
            dp += __shfl_xor(dp, 2);  np += __shfl_xor(np, 2);
            const float un  = unj - u_i;
            const float dot = dp + uv * un;
            const float nn2 = np + un * un;
            const float rn  = (nn2 > 0.0f) ? rsqrtf(nn2) : 0.0f;
            maxq = fmaxf(maxq, dot * rn);
        }
        if (q == 0) cost = 1.0f - maxq * inv_vi;
    }
    for (int off = 32; off > 0; off >>= 1) cost += __shfl_down(cost, off);
    __shared__ float wsum[BLOCK / 64];
    if ((tid & 63) == 0) wsum[tid >> 6] = cost;
    __syncthreads();
    if (tid == 0) {
        float s = 0.0f;
        #pragma unroll
        for (int wv = 0; wv < BLOCK / 64; ++wv) s += wsum[wv];
        partials[blockIdx.x] = s;
    }
}

__global__ __launch_bounds__(BLOCK) void final_reduce_kernel(
    const float* __restrict__ partials, int nparts, float* __restrict__ out)
{
    float s = 0.0f;
    for (int i = threadIdx.x; i < nparts; i += BLOCK) s += partials[i];
    for (int off = 32; off > 0; off >>= 1) s += __shfl_down(s, off);
    __shared__ float wsum[BLOCK / 64];
    if ((threadIdx.x & 63) == 0) wsum[threadIdx.x >> 6] = s;
    __syncthreads();
    if (threadIdx.x == 0) {
        float t = 0.0f;
        #pragma unroll
        for (int wv = 0; wv < BLOCK / 64; ++wv) t += wsum[wv];
        out[0] = t / (float)N_CELLS_C;
    }
}

extern "C" void kernel_launch(void* const* d_in, const int* in_sizes, int n_in,
                              void* d_out, int out_size, void* d_ws, size_t ws_size,
                              hipStream_t stream) {
    const float* unsplice         = (const float*)d_in[0];
    const float* splices          = (const float*)d_in[1];
    const float* unsplice_predict = (const float*)d_in[2];
    const float* splice_predicts  = (const float*)d_in[3];
    const char*  idx_bytes        = (const char*)d_in[4];
    float* out = (float*)d_out;

    // ws layout: [rec 3.2MB][u16 0.2MB][partials]
    char*      rec      = (char*)d_ws;
    _Float16*  u16      = (_Float16*)((char*)d_ws + (size_t)N_CELLS_C * 32);
    float*     partials = (float*)((char*)d_ws + 3400000);

    const size_t req = 3400000 + 4 * 4096;

    if (ws_size >= req) {
        const int pack_blocks = (2 * N_CELLS_C + BLOCK - 1) / BLOCK;
        pack_kernel<<<pack_blocks, BLOCK, 0, stream>>>(unsplice, splices, rec, u16);
        const int nblocks = N_CELLS_C / (BLOCK / 8);   // 3125, exact
        cost_kernel_h<<<nblocks, BLOCK, 0, stream>>>(
            unsplice, splices, unsplice_predict, splice_predicts,
            idx_bytes, rec, u16, partials);
        final_reduce_kernel<<<1, BLOCK, 0, stream>>>(partials, nblocks, out);
    } else {
        float* fb_partials = (float*)d_ws;
        const int nblocks = (N_CELLS_C + (BLOCK / 4) - 1) / (BLOCK / 4);
        cost_kernel_f32<<<nblocks, BLOCK, 0, stream>>>(
            unsplice, splices, unsplice_predict, splice_predicts,
            idx_bytes, fb_partials);
        final_reduce_kernel<<<1, BLOCK, 0, stream>>>(fb_partials, nblocks, out);
    }
}